// Round 5
// baseline (128.780 us; speedup 1.0000x reference)
//
#include <hip/hip_runtime.h>
#include <hip/hip_cooperative_groups.h>
#include <cstdint>
#include <cstddef>

namespace cg = cooperative_groups;

#define NPTS 8192
#define NWORDS 128          // NPTS/64
#define XCOLS 10            // 3 coords + batch + feat + 5 seg
#define MIN_PTS 5
#define NGROUPS 10
#define BIGC 0x3fffffff

#define NLCAP 1536          // max nodes per group (expect ~820)
#define ELCAP 8192          // core-core edges (expect ~5k)
#define EBCAP 2048          // core-noncore edges (expect ~500)
#define NSLICE 24           // row slices per group (rows r == s mod 24)
#define ECAP_S 1024         // per-slice edge region cap (expect ~225/slice)
#define NT 1024             // 16 waves
#define NWV 16
#define ROUNDS 16

// ---- LDS layouts (union'd via raw buffer; graph layout is the larger) ------
struct SmemP {                       // pairs phase: ~26.4 KB
    float4 pts[NLCAP];
    unsigned long long masks[NWORDS];
    int pref[NWORDS];
    int srowdeg[64];
    int scnt, nnS;
};
struct SmemG {                       // graph phase: ~72.5 KB
    unsigned int eL[ELCAP];
    unsigned int eB[EBCAP];
    int sdeg[NLCAP];
    int spar[NLCAP];
    int scid[NLCAP];
    int sbmin[NLCAP];
    int nlist[NLCAP];
    unsigned int corebm32[NLCAP / 32];
    unsigned long long repbm[NLCAP / 64];
    int pref24[NLCAP / 64];
    int cntE[NSLICE];
    int nL, nB;
    int sflagA[ROUNDS];
};

// ---------------- pairs phase: membership + slice adjacency ------------------
// Block (g,s): rebuilds group g's ordered node list from x (ballot+prefix),
// fills pts in LDS (w = 0.5|p|^2 - EPS2/4; test: dot > wu+wv), computes rows
// r == s (mod 24) (one row per lane; 16 waves partition the 32-col chunks).
// Edges (u<v) go to a PRIVATE per-slice global region with a plain-stored
// count -> no counter zeroing anywhere. Full-row degrees plain-stored.
__device__ __forceinline__ void do_pairs(const float* __restrict__ x, int g, int s,
        SmemP& sm, unsigned int* __restrict__ eAll, int* __restrict__ ecnt,
        int* __restrict__ deg_g, int* __restrict__ nlist_g, int* __restrict__ nn_g) {
    const int tid = threadIdx.x, lane = tid & 63, wv = tid >> 6;

    for (int k = tid; k < NLCAP; k += NT)
        sm.pts[k] = make_float4(0.f, 0.f, 0.f, 1.0e38f);   // sentinel: never matches
    if (tid < 64) sm.srowdeg[tid] = 0;
    if (tid == 0) sm.scnt = 0;

    for (int w = wv; w < NWORDS; w += NWV) {
        int i = w * 64 + lane;
        const float2* r2 = (const float2*)(x + (size_t)i * XCOLS);  // rows 40 B, 8-aligned
        float2 c23 = r2[1];                 // z, batch
        float2 c45 = r2[2];                 // feat, s0
        float2 c67 = r2[3];                 // s1, s2
        float2 c89 = r2[4];                 // s3, s4
        float best = c45.y; int bc = 0;
        if (c67.x > best) { best = c67.x; bc = 1; }
        if (c67.y > best) { best = c67.y; bc = 2; }
        if (c89.x > best) { best = c89.x; bc = 3; }
        if (c89.y > best) { best = c89.y; bc = 4; }
        unsigned long long bm = __ballot((int)c23.y * 5 + bc == g);
        if (lane == 0) sm.masks[w] = bm;
    }
    __syncthreads();
    if (wv == 0) {                          // 2-chunk scan of 128 popcounts
        int v0 = __popcll(sm.masks[lane]);
        int incl = v0;
        #pragma unroll
        for (int st = 1; st < 64; st <<= 1) {
            int o = __shfl_up(incl, st);
            if (lane >= st) incl += o;
        }
        sm.pref[lane] = incl - v0;
        int tot0 = __shfl(incl, 63);
        int v1 = __popcll(sm.masks[64 + lane]);
        int incl1 = v1;
        #pragma unroll
        for (int st = 1; st < 64; st <<= 1) {
            int o = __shfl_up(incl1, st);
            if (lane >= st) incl1 += o;
        }
        sm.pref[64 + lane] = tot0 + incl1 - v1;
        if (lane == 63) sm.nnS = tot0 + incl1;
    }
    __syncthreads();
    for (int w = wv; w < NWORDS; w += NWV) {
        unsigned long long bm = sm.masks[w];
        if ((bm >> lane) & 1ull) {
            int p = sm.pref[w] + __popcll(bm & ((1ull << lane) - 1ull));
            if (p < NLCAP) {
                int i = w * 64 + lane;
                const float2* r2 = (const float2*)(x + (size_t)i * XCOLS);
                float2 c01 = r2[0]; float2 c23 = r2[1];
                float px = c01.x, py = c01.y, pz = c23.x;
                // d2<EPS2  <=>  dot(u,v) > wu+wv  with w = 0.5|p|^2 - EPS2/4
                sm.pts[p] = make_float4(px, py, pz,
                                        0.5f * (px*px + py*py + pz*pz) - 56.25f);
                if (s == 0) nlist_g[g * NLCAP + p] = i;
            }
        }
    }
    if (s == 0 && tid == 0) nn_g[g] = (sm.nnS > NLCAP) ? NLCAP : sm.nnS;
    __syncthreads();
    const int NN = (sm.nnS > NLCAP) ? NLCAP : sm.nnS;

    const int rrow = s + NSLICE * lane;               // covers 0..1535 exactly
    const float4 qu = sm.pts[rrow];
    int rdeg = 0;
    const int NC = (NN + 31) >> 5;
    unsigned int* eg = eAll + (size_t)(g * NSLICE + s) * ECAP_S;
    for (int c = wv; c < NC; c += NWV) {
        int base = c << 5;
        unsigned int bits = 0u;
        #pragma unroll
        for (int t = 0; t < 32; t++) {
            float4 qv = sm.pts[base + t];             // wave-uniform broadcast
            float dt = qu.x*qv.x + qu.y*qv.y + qu.z*qv.z;
            bits |= (dt > qu.w + qv.w) ? (1u << t) : 0u;
        }
        rdeg += __popc(bits);                          // full row degree (incl self)
        int d = rrow - base;                           // keep only v > u for edges
        if (d >= 31) bits = 0u;
        else if (d >= 0) bits &= ~((2u << d) - 1u);
        int cnt = __popc(bits);
        int incl = cnt;
        #pragma unroll
        for (int st = 1; st < 64; st <<= 1) {
            int o = __shfl_up(incl, st);
            if (lane >= st) incl += o;
        }
        int tot = __shfl(incl, 63);
        if (tot > 0) {
            int rb = 0;
            if (lane == 63) rb = atomicAdd(&sm.scnt, tot);
            rb = __shfl(rb, 63);
            unsigned int p = (unsigned int)(rb + incl - cnt);
            unsigned int b = bits;
            unsigned int uhi = (unsigned int)rrow << 11;
            while (b) {
                int t = __ffs(b) - 1; b &= b - 1;
                if (p < ECAP_S) eg[p] = uhi | (unsigned int)(base + t);
                p++;
            }
        }
    }
    if (rdeg > 0) atomicAdd(&sm.srowdeg[lane], rdeg); // sum across the 16 waves
    __syncthreads();
    if (tid < 64)
        deg_g[g * NLCAP + s + NSLICE * tid] = sm.srowdeg[tid];
    if (tid == 0)
        ecnt[g * NSLICE + s] = (sm.scnt > ECAP_S) ? ECAP_S : sm.scnt;   // plain store
}

// ---------------- graph phase: core -> classify -> SV -> rank -> output ------
__device__ __forceinline__ void do_graph(const float* __restrict__ x, int g,
        SmemG& sm, const unsigned int* __restrict__ eAll, const int* __restrict__ ecnt,
        const int* __restrict__ deg_g, const int* __restrict__ nlist_g,
        const int* __restrict__ nn_g, float* __restrict__ out) {
    const int tid = threadIdx.x, lane = tid & 63, wv = tid >> 6;
    const int NN = nn_g[g];

    if (tid == 0) { sm.nL = 0; sm.nB = 0; }
    if (tid < ROUNDS) sm.sflagA[tid] = 0;
    if (wv == 0 && lane < NSLICE) {
        int c = ecnt[g * NSLICE + lane];
        sm.cntE[lane] = (c > ECAP_S) ? ECAP_S : c;
    }
    for (int k = tid; k < NLCAP; k += NT) {
        sm.sdeg[k] = deg_g[g * NLCAP + k];
        sm.spar[k] = k;
        sm.sbmin[k] = BIGC;
        sm.nlist[k] = nlist_g[g * NLCAP + k];
    }
    __syncthreads();
    for (int wd = tid; wd < NLCAP / 32; wd += NT) {    // core bitmap
        unsigned int m = 0u;
        #pragma unroll
        for (int j = 0; j < 32; j++)
            m |= (sm.sdeg[wd * 32 + j] >= MIN_PTS) ? (1u << j) : 0u;
        sm.corebm32[wd] = m;
    }
    __syncthreads();
    auto corebit = [&](int l) -> bool { return (sm.corebm32[l >> 5] >> (l & 31)) & 1u; };

    // classify per-slice edge regions -> eL / eB (wave-aggregated compaction)
    for (int s2 = 0; s2 < NSLICE; s2++) {
        int cE = sm.cntE[s2];
        const unsigned int* eg = eAll + (size_t)(g * NSLICE + s2) * ECAP_S;
        for (int e0 = 0; e0 < cE; e0 += NT) {
            int e = e0 + tid;
            bool val = e < cE;
            unsigned int pk = val ? eg[e] : 0u;
            int u = (int)(pk >> 11), v = (int)(pk & 2047u);
            bool cu = val && corebit(u), cv = val && corebit(v);
            bool isL = cu && cv, isB = val && (cu != cv);
            unsigned long long mL = __ballot(isL);
            if (mL) {
                int b0 = 0;
                if (lane == 0) b0 = atomicAdd(&sm.nL, __popcll(mL));
                b0 = __shfl(b0, 0);
                if (isL) {
                    int idx = b0 + __popcll(mL & ((1ull << lane) - 1ull));
                    if (idx < ELCAP) sm.eL[idx] = pk;
                }
            }
            unsigned long long mB = __ballot(isB);
            if (mB) {
                int b0 = 0;
                if (lane == 0) b0 = atomicAdd(&sm.nB, __popcll(mB));
                b0 = __shfl(b0, 0);
                if (isB) {
                    int idx = b0 + __popcll(mB & ((1ull << lane) - 1ull));
                    if (idx < EBCAP) sm.eB[idx] = pk;
                }
            }
        }
    }
    __syncthreads();
    const int NL = (sm.nL > ELCAP) ? ELCAP : sm.nL;
    const int NB = (sm.nB > EBCAP) ? EBCAP : sm.nB;

    // SV: find-root hook + full path compression (values only decrease)
    for (int r = 0; r < ROUNDS; r++) {
        for (int k = tid; k < NL; k += NT) {
            unsigned int pk = sm.eL[k];
            int u = (int)(pk >> 11), v = (int)(pk & 2047u);
            int ru = sm.spar[u];
            while (true) { int p = sm.spar[ru]; if (p == ru) break; ru = p; }
            int rv = sm.spar[v];
            while (true) { int p = sm.spar[rv]; if (p == rv) break; rv = p; }
            if (ru < rv)      { if (atomicMin(&sm.spar[rv], ru) > ru) sm.sflagA[r] = 1; }
            else if (rv < ru) { if (atomicMin(&sm.spar[ru], rv) > rv) sm.sflagA[r] = 1; }
        }
        __syncthreads();
        for (int k = tid; k < NN; k += NT) {
            int p = sm.spar[k];
            while (true) { int q = sm.spar[p]; if (q == p) break; p = q; }
            sm.spar[k] = p;
        }
        __syncthreads();
        if (!sm.sflagA[r]) break;
    }

    // reps bitmap + parallel rank over 24 words
    for (int w = wv; w < NLCAP / 64; w += NWV) {
        int l = w * 64 + lane;
        bool isr = (l < NN) && corebit(l) && (sm.spar[l] == l);
        unsigned long long bm = __ballot(isr);
        if (lane == 0) sm.repbm[w] = bm;
    }
    __syncthreads();
    if (wv == 0 && lane < NLCAP / 64) {
        int c = __popcll(sm.repbm[lane]);
        int incl = c;
        #pragma unroll
        for (int st = 1; st < 32; st <<= 1) {
            int o = __shfl_up(incl, st);
            if (lane >= st) incl += o;
        }
        sm.pref24[lane] = incl - c;
    }
    __syncthreads();
    for (int w = wv; w < NLCAP / 64; w += NWV) {
        int l = w * 64 + lane;
        unsigned long long bm = sm.repbm[w];
        if ((bm >> lane) & 1ull)
            sm.scid[l] = sm.pref24[w] + __popcll(bm & ((1ull << lane) - 1ull));
    }
    __syncthreads();
    // core cluster id -> overwrite spar (read-all then write-all)
    int cc[2];
    #pragma unroll
    for (int t = 0; t < 2; t++) {
        int k = tid + t * NT;
        cc[t] = (k < NN && corebit(k)) ? sm.scid[sm.spar[k]] : BIGC;
    }
    __syncthreads();
    #pragma unroll
    for (int t = 0; t < 2; t++) {
        int k = tid + t * NT;
        if (k < NLCAP) sm.spar[k] = (k < NN) ? cc[t] : BIGC;
    }
    __syncthreads();
    // border: min adjacent core cid for the non-core endpoint
    for (int k = tid; k < NB; k += NT) {
        unsigned int pk = sm.eB[k];
        int u = (int)(pk >> 11), v = (int)(pk & 2047u);
        int cu = sm.spar[u], cv = sm.spar[v];
        if (cu == BIGC) atomicMin(&sm.sbmin[u], cv);
        else            atomicMin(&sm.sbmin[v], cu);
    }
    __syncthreads();
    // final labels + clustered output (groups cover disjoint point sets)
    for (int k = tid; k < NN; k += NT) {
        int i = sm.nlist[k];
        int c = sm.spar[k];
        int lbl = (c != BIGC) ? c : ((sm.sbmin[k] < BIGC) ? sm.sbmin[k] : -1);
        out[i] = (float)lbl;
        const float* r = x + (size_t)i * XCOLS;
        float* o = out + NPTS + (size_t)i * 5;
        bool keep = lbl >= 0;
        #pragma unroll
        for (int c5 = 0; c5 < 5; c5++) o[c5] = keep ? r[c5] : 0.0f;
    }
}

// ---------------- cooperative fused kernel + non-coop fallbacks --------------
__global__ void __launch_bounds__(NT) k_fused(const float* __restrict__ x,
        float* __restrict__ out, unsigned int* __restrict__ eAll,
        int* __restrict__ ecnt, int* __restrict__ deg_g,
        int* __restrict__ nlist_g, int* __restrict__ nn_g) {
    __shared__ __align__(16) char smem[sizeof(SmemG)];   // >= sizeof(SmemP)
    const int g = blockIdx.x / NSLICE, s = blockIdx.x % NSLICE;
    do_pairs(x, g, s, *reinterpret_cast<SmemP*>(smem), eAll, ecnt, deg_g, nlist_g, nn_g);
    cg::this_grid().sync();
    if (s == 0)
        do_graph(x, g, *reinterpret_cast<SmemG*>(smem), eAll, ecnt, deg_g,
                 nlist_g, nn_g, out);
}

__global__ void __launch_bounds__(NT) k_pairs_f(const float* __restrict__ x,
        unsigned int* __restrict__ eAll, int* __restrict__ ecnt,
        int* __restrict__ deg_g, int* __restrict__ nlist_g, int* __restrict__ nn_g) {
    __shared__ __align__(16) char smem[sizeof(SmemP)];
    const int g = blockIdx.x / NSLICE, s = blockIdx.x % NSLICE;
    do_pairs(x, g, s, *reinterpret_cast<SmemP*>(smem), eAll, ecnt, deg_g, nlist_g, nn_g);
}

__global__ void __launch_bounds__(NT) k_graph_f(const float* __restrict__ x,
        const unsigned int* __restrict__ eAll, const int* __restrict__ ecnt,
        const int* __restrict__ deg_g, const int* __restrict__ nlist_g,
        const int* __restrict__ nn_g, float* __restrict__ out) {
    __shared__ __align__(16) char smem[sizeof(SmemG)];
    do_graph(x, blockIdx.x, *reinterpret_cast<SmemG*>(smem), eAll, ecnt, deg_g,
             nlist_g, nn_g, out);
}

extern "C" void kernel_launch(void* const* d_in, const int* in_sizes, int n_in,
                              void* d_out, int out_size, void* d_ws, size_t ws_size,
                              hipStream_t stream) {
    const float* x = (const float*)d_in[0];
    float* out = (float*)d_out;
    char* ws = (char*)d_ws;

    // workspace layout (~1.08 MB); nothing needs pre-zeroing
    unsigned int* eAll  = (unsigned int*)(ws);            // 240*1024*4 = 983040
    int* ecnt           = (int*)(ws + 983040);            // 240*4 (pad to 1024)
    int* deg_g          = (int*)(ws + 984064);            // 10*1536*4 = 61440
    int* nlist_g        = (int*)(ws + 1045504);           // 61440
    int* nn_g           = (int*)(ws + 1106944);           // 64

    void* args[] = { (void*)&x, (void*)&out, (void*)&eAll, (void*)&ecnt,
                     (void*)&deg_g, (void*)&nlist_g, (void*)&nn_g };
    hipError_t err = hipLaunchCooperativeKernel((const void*)k_fused,
                        dim3(NGROUPS * NSLICE), dim3(NT), args, 0, stream);
    if (err != hipSuccess) {
        (void)hipGetLastError();    // clear sticky error, fall back to 2 dispatches
        k_pairs_f<<<NGROUPS * NSLICE, NT, 0, stream>>>(x, eAll, ecnt, deg_g,
                                                       nlist_g, nn_g);
        k_graph_f<<<NGROUPS, NT, 0, stream>>>(x, eAll, ecnt, deg_g, nlist_g,
                                              nn_g, out);
    }
}

// Round 6
// 88.584 us; speedup vs baseline: 1.4537x; 1.4537x over previous
//
#include <hip/hip_runtime.h>
#include <cstdint>
#include <cstddef>

#define NPTS 8192
#define NWORDS 128          // NPTS/64
#define XCOLS 10            // 3 coords + batch + feat + 5 seg
#define MIN_PTS 5
#define NGROUPS 10
#define BIGC 0x3fffffff

#define NLCAP 1536          // max nodes per group (expect ~820)
#define NSLICE 24           // row slices per group (rows r == s mod 24)
#define ECAP_S 2048         // per-slice edge region cap (expect ~225/slice)
#define EACAP 8192          // LDS staged edges per group (expect ~5.4k)
#define PT 512              // k_pairs threads (8 waves)
#define PWV 8
#define GT 1024             // k_graph threads (16 waves)
#define GWV 16
#define ROUNDS 16
#define FLAG_B 0x80000000u  // border edge (exactly one core endpoint)
#define FLAG_D 0x40000000u  // dead edge (no core endpoint)

// ---------------- pairs: membership + row-slice adjacency --------------------
// Block (g,s): rebuilds group g's ordered node list from x (ballot+prefix),
// fills pts in LDS (w = 0.5|p|^2 - EPS2/4; test: dot > wu+wv), computes rows
// r == s (mod 24), one row per lane, 8 waves partition 32-col chunks.
// Outputs (ALL plain stores, nothing pre-zeroed):
//   eAll[(g*24+s)*ECAP_S + .]  packed edges u<v        ecnt[g*24+s] count
//   corebm_g[g*24+s]           ballot: bit l = core(row s+24l)
//   nlist_g / nn_g             from slice 0 only
__global__ void __launch_bounds__(PT) k_pairs(
        const float* __restrict__ x, unsigned int* __restrict__ eAll,
        int* __restrict__ ecnt, unsigned long long* __restrict__ corebm_g,
        int* __restrict__ nlist_g, int* __restrict__ nn_g) {
    __shared__ float4 pts[NLCAP];                    // 24 KB
    __shared__ unsigned long long masks[NWORDS];     // 1 KB
    __shared__ int pref[NWORDS];                     // 0.5 KB
    __shared__ int srowdeg[64];
    __shared__ int scnt, nnS;

    const int g = blockIdx.x / NSLICE;
    const int s = blockIdx.x % NSLICE;
    const int tid = threadIdx.x, lane = tid & 63, wv = tid >> 6;

    for (int k = tid; k < NLCAP; k += PT)
        pts[k] = make_float4(0.f, 0.f, 0.f, 1.0e38f);     // sentinel: never matches
    if (tid < 64) srowdeg[tid] = 0;
    if (tid == 0) scnt = 0;

    for (int w = wv; w < NWORDS; w += PWV) {
        int i = w * 64 + lane;
        const float2* r2 = (const float2*)(x + (size_t)i * XCOLS);  // rows 40 B, 8-aligned
        float2 c23 = r2[1];                 // z, batch
        float2 c45 = r2[2];                 // feat, s0
        float2 c67 = r2[3];                 // s1, s2
        float2 c89 = r2[4];                 // s3, s4
        float best = c45.y; int bc = 0;
        if (c67.x > best) { best = c67.x; bc = 1; }
        if (c67.y > best) { best = c67.y; bc = 2; }
        if (c89.x > best) { best = c89.x; bc = 3; }
        if (c89.y > best) { best = c89.y; bc = 4; }
        unsigned long long bm = __ballot((int)c23.y * 5 + bc == g);
        if (lane == 0) masks[w] = bm;
    }
    __syncthreads();
    if (wv == 0) {                          // 2-chunk scan of 128 popcounts
        int v0 = __popcll(masks[lane]);
        int incl = v0;
        #pragma unroll
        for (int st = 1; st < 64; st <<= 1) {
            int o = __shfl_up(incl, st);
            if (lane >= st) incl += o;
        }
        pref[lane] = incl - v0;
        int tot0 = __shfl(incl, 63);
        int v1 = __popcll(masks[64 + lane]);
        int incl1 = v1;
        #pragma unroll
        for (int st = 1; st < 64; st <<= 1) {
            int o = __shfl_up(incl1, st);
            if (lane >= st) incl1 += o;
        }
        pref[64 + lane] = tot0 + incl1 - v1;
        if (lane == 63) nnS = tot0 + incl1;
    }
    __syncthreads();
    for (int w = wv; w < NWORDS; w += PWV) {
        unsigned long long bm = masks[w];
        if ((bm >> lane) & 1ull) {
            int p = pref[w] + __popcll(bm & ((1ull << lane) - 1ull));
            if (p < NLCAP) {
                int i = w * 64 + lane;
                const float2* r2 = (const float2*)(x + (size_t)i * XCOLS);
                float2 c01 = r2[0]; float2 c23 = r2[1];
                float px = c01.x, py = c01.y, pz = c23.x;
                // d2<EPS2  <=>  dot(u,v) > wu+wv  with w = 0.5|p|^2 - EPS2/4
                pts[p] = make_float4(px, py, pz,
                                     0.5f * (px*px + py*py + pz*pz) - 56.25f);
                if (s == 0) nlist_g[g * NLCAP + p] = i;
            }
        }
    }
    if (s == 0 && tid == 0) nn_g[g] = (nnS > NLCAP) ? NLCAP : nnS;
    __syncthreads();
    const int NN = (nnS > NLCAP) ? NLCAP : nnS;

    const int rrow = s + NSLICE * lane;               // covers 0..1535 exactly
    const float4 qu = pts[rrow];
    int rdeg = 0;
    const int NC = (NN + 31) >> 5;
    unsigned int* eg = eAll + (size_t)(g * NSLICE + s) * ECAP_S;
    for (int c = wv; c < NC; c += PWV) {
        int base = c << 5;
        unsigned int bits = 0u;
        #pragma unroll
        for (int t = 0; t < 32; t++) {
            float4 qv = pts[base + t];                // wave-uniform broadcast
            float dt = qu.x*qv.x + qu.y*qv.y + qu.z*qv.z;
            bits |= (dt > qu.w + qv.w) ? (1u << t) : 0u;
        }
        rdeg += __popc(bits);                          // full row degree (incl self)
        int d = rrow - base;                           // keep only v > u for edges
        if (d >= 31) bits = 0u;
        else if (d >= 0) bits &= ~((2u << d) - 1u);
        int cnt = __popc(bits);
        int incl = cnt;
        #pragma unroll
        for (int st = 1; st < 64; st <<= 1) {
            int o = __shfl_up(incl, st);
            if (lane >= st) incl += o;
        }
        int tot = __shfl(incl, 63);
        if (tot > 0) {
            int rb = 0;
            if (lane == 63) rb = atomicAdd(&scnt, tot);
            rb = __shfl(rb, 63);
            unsigned int p = (unsigned int)(rb + incl - cnt);
            unsigned int b = bits;
            unsigned int uhi = (unsigned int)rrow << 11;
            while (b) {
                int t = __ffs(b) - 1; b &= b - 1;
                if (p < ECAP_S) eg[p] = uhi | (unsigned int)(base + t);
                p++;
            }
        }
    }
    if (rdeg > 0) atomicAdd(&srowdeg[lane], rdeg);    // sum across the 8 waves
    __syncthreads();
    if (wv == 0) {
        // bit l of corebm = core status of row s + 24*l (this block owns them)
        unsigned long long cb = __ballot(srowdeg[lane] >= MIN_PTS);
        if (lane == 0) {
            corebm_g[g * NSLICE + s] = cb;
            ecnt[g * NSLICE + s] = (scnt > ECAP_S) ? ECAP_S : scnt;
        }
    }
}

// ---------------- graph: stage -> SV(classify in-place) -> rank -> output ----
__global__ void __launch_bounds__(GT) k_graph(
        const unsigned int* __restrict__ eAll, const int* __restrict__ ecnt,
        const unsigned long long* __restrict__ corebm_g,
        const int* __restrict__ nlist_g, const int* __restrict__ nn_g,
        const float* __restrict__ x, float* __restrict__ out) {
    __shared__ unsigned int eA[EACAP];               // 32 KB
    __shared__ int spar[NLCAP];                      // 6 KB
    __shared__ int scid[NLCAP];                      // 6 KB
    __shared__ int sbmin[NLCAP];                     // 6 KB
    __shared__ int nlist[NLCAP];                     // 6 KB
    __shared__ unsigned long long cbm[NSLICE];       // (s,l) layout from pairs
    __shared__ unsigned long long corelin[NLCAP/64]; // linear-index layout
    __shared__ unsigned long long repbm[NLCAP/64];
    __shared__ int pref24[NLCAP/64];
    __shared__ int offs[NSLICE], cnts[NSLICE];
    __shared__ int NAs;
    __shared__ int sflagA[ROUNDS];

    const int g = blockIdx.x;
    const int tid = threadIdx.x, lane = tid & 63, wv = tid >> 6;
    const int NN = nn_g[g];

    if (tid < ROUNDS) sflagA[tid] = 0;
    if (wv == 0) {                                   // counts -> prefix, masks
        int c = 0;
        if (lane < NSLICE) {
            c = ecnt[g * NSLICE + lane];
            c = (c > ECAP_S) ? ECAP_S : c;
            cbm[lane] = corebm_g[g * NSLICE + lane];
        }
        int incl = c;
        #pragma unroll
        for (int st = 1; st < 32; st <<= 1) {
            int o = __shfl_up(incl, st);
            if (lane >= st) incl += o;
        }
        if (lane < NSLICE) { offs[lane] = incl - c; cnts[lane] = c; }
        if (lane == NSLICE - 1) NAs = incl;
    }
    for (int k = tid; k < NLCAP; k += GT) {
        spar[k] = k;
        sbmin[k] = BIGC;
        nlist[k] = nlist_g[g * NLCAP + k];
    }
    __syncthreads();
    const int NA = (NAs > EACAP) ? EACAP : NAs;
    // stage per-slice edge regions contiguously into LDS; repack core bitmap
    for (int s2 = wv; s2 < NSLICE; s2 += GWV) {
        const unsigned int* eg = eAll + (size_t)(g * NSLICE + s2) * ECAP_S;
        int off = offs[s2], cn = cnts[s2];
        for (int o = lane; o < cn; o += 64) {
            int dst = off + o;
            if (dst < EACAP) eA[dst] = eg[o];
        }
    }
    for (int w = wv; w < NLCAP / 64; w += GWV) {     // (s,l) -> linear bitmap
        int l = w * 64 + lane;
        bool b = (cbm[l % NSLICE] >> (l / NSLICE)) & 1ull;
        unsigned long long bm = __ballot(b);
        if (lane == 0) corelin[w] = bm;
    }
    __syncthreads();
    auto corebit = [&](int l) -> bool { return (corelin[l >> 6] >> (l & 63)) & 1ull; };

    // SV: round 0 classifies in-place (flag border/dead), hooks core-core;
    // later rounds skip flagged. find-root hook + full path compression.
    for (int r = 0; r < ROUNDS; r++) {
        for (int k = tid; k < NA; k += GT) {
            unsigned int pk = eA[k];
            if (pk & 0xC0000000u) continue;
            int u = (int)((pk >> 11) & 2047u), v = (int)(pk & 2047u);
            if (r == 0) {
                bool cu = corebit(u), cv = corebit(v);
                if (!(cu && cv)) {
                    eA[k] = pk | ((cu != cv) ? FLAG_B : FLAG_D);
                    continue;
                }
            }
            int ru = spar[u];
            while (true) { int p = spar[ru]; if (p == ru) break; ru = p; }
            int rv = spar[v];
            while (true) { int p = spar[rv]; if (p == rv) break; rv = p; }
            if (ru < rv)      { if (atomicMin(&spar[rv], ru) > ru) sflagA[r] = 1; }
            else if (rv < ru) { if (atomicMin(&spar[ru], rv) > rv) sflagA[r] = 1; }
        }
        __syncthreads();
        for (int k = tid; k < NN; k += GT) {
            int p = spar[k];
            while (true) { int q = spar[p]; if (q == p) break; p = q; }
            spar[k] = p;
        }
        __syncthreads();
        if (!sflagA[r]) break;
    }

    // reps bitmap + parallel rank over 24 words
    for (int w = wv; w < NLCAP / 64; w += GWV) {
        int l = w * 64 + lane;
        bool isr = (l < NN) && corebit(l) && (spar[l] == l);
        unsigned long long bm = __ballot(isr);
        if (lane == 0) repbm[w] = bm;
    }
    __syncthreads();
    if (wv == 0 && lane < NLCAP / 64) {
        int c = __popcll(repbm[lane]);
        int incl = c;
        #pragma unroll
        for (int st = 1; st < 32; st <<= 1) {
            int o = __shfl_up(incl, st);
            if (lane >= st) incl += o;
        }
        pref24[lane] = incl - c;
    }
    __syncthreads();
    for (int w = wv; w < NLCAP / 64; w += GWV) {
        int l = w * 64 + lane;
        unsigned long long bm = repbm[w];
        if ((bm >> lane) & 1ull)
            scid[l] = pref24[w] + __popcll(bm & ((1ull << lane) - 1ull));
    }
    __syncthreads();
    // core cluster id -> overwrite spar (read-all then write-all)
    int cc[2];
    #pragma unroll
    for (int t = 0; t < 2; t++) {
        int k = tid + t * GT;
        cc[t] = (k < NN && corebit(k)) ? scid[spar[k]] : BIGC;
    }
    __syncthreads();
    #pragma unroll
    for (int t = 0; t < 2; t++) {
        int k = tid + t * GT;
        if (k < NLCAP) spar[k] = (k < NN) ? cc[t] : BIGC;
    }
    __syncthreads();
    // border: min adjacent core cid for the non-core endpoint
    for (int k = tid; k < NA; k += GT) {
        unsigned int pk = eA[k];
        if ((pk & 0xC0000000u) != FLAG_B) continue;
        int u = (int)((pk >> 11) & 2047u), v = (int)(pk & 2047u);
        int cu = spar[u], cv = spar[v];
        if (cu == BIGC) atomicMin(&sbmin[u], cv);
        else            atomicMin(&sbmin[v], cu);
    }
    __syncthreads();
    // final labels + clustered output (groups cover disjoint point sets)
    for (int k = tid; k < NN; k += GT) {
        int i = nlist[k];
        int c = spar[k];
        int lbl = (c != BIGC) ? c : ((sbmin[k] < BIGC) ? sbmin[k] : -1);
        out[i] = (float)lbl;
        const float* r = x + (size_t)i * XCOLS;
        float* o = out + NPTS + (size_t)i * 5;
        bool keep = lbl >= 0;
        #pragma unroll
        for (int c5 = 0; c5 < 5; c5++) o[c5] = keep ? r[c5] : 0.0f;
    }
}

extern "C" void kernel_launch(void* const* d_in, const int* in_sizes, int n_in,
                              void* d_out, int out_size, void* d_ws, size_t ws_size,
                              hipStream_t stream) {
    const float* x = (const float*)d_in[0];
    float* out = (float*)d_out;
    char* ws = (char*)d_ws;

    // workspace (~2.03 MB); NOTHING needs pre-zeroing (plain-stored counts/masks)
    unsigned int* eAll       = (unsigned int*)(ws);              // 240*2048*4 = 1966080
    int* ecnt                = (int*)(ws + 1966080);             // 240*4 (pad 1024)
    unsigned long long* cbm  = (unsigned long long*)(ws + 1967104); // 240*8 = 1920
    int* nlist_g             = (int*)(ws + 1969024);             // 61440
    int* nn_g                = (int*)(ws + 2030464);             // 64

    k_pairs<<<NGROUPS * NSLICE, PT, 0, stream>>>(x, eAll, ecnt, cbm, nlist_g, nn_g);
    k_graph<<<NGROUPS, GT, 0, stream>>>(eAll, ecnt, cbm, nlist_g, nn_g, x, out);
}